// Round 1
// 264.645 us; speedup vs baseline: 1.5083x; 1.5083x over previous
//
#include <hip/hip_runtime.h>

// SymplecticLayer: 2 leapfrog steps; force = grad of tanh-MLP Hamiltonian (8->128->128->1).
// v2 structure:
//   - prep kernel (once per launch, 65 blocks) pre-swizzles fp8 weight fragments into d_ws
//   - main kernel stages fragments via global_load_lds (16B), no per-block scatter swizzle
//   - activations: column-major fp8 tile per wave; packed ds_write_b32 (conflict-free),
//     A-fragments read with gfx950 ds_read_b64_tr_b8 hardware transpose
//   - L2fwd/L2bwd/L1bwd use K=128 mfma_scale f8f6f4 with unit scales (25 MFMAs/eval vs 76)
//   - folds: W1B,W2B *= 2*log2e (tanh via exp2, no mul); bias in acc init; W2T *= S1/S2;
//     d2 = 64*W3*(r-r^2) with r=1/(e+1)  [1-tanh^2 = 4(r-r^2)]

typedef float f32x4 __attribute__((ext_vector_type(4)));
typedef int   i32x2 __attribute__((ext_vector_type(2)));
typedef int   i32x4 __attribute__((ext_vector_type(4)));
typedef int   i32x8 __attribute__((ext_vector_type(8)));

#define DT 0.01f
#define S1 64.0f              // d1 scale (avoid e4m3 denormals)
#define S2 16.0f              // d2 scale
#define TWO_LOG2E 2.8853900817779268f
#define SCL1 0x7F7F7F7F       // e8m0 1.0 in all four bytes

// workspace / LDS fragment layout (fp8 bytes). K=128 regions use the byte map:
//   register byte p (0..31) of quad qd  <->  k = 32*(p>>3) + 8*qd + (p&7)
// identical on A and B sides, so any internal HW k-permutation cancels.
#define OFF_W1B 0             // 4096 : L1 fwd B-frags, K=32 (k>=8 zero), scaled 2log2e
#define OFF_W2B 4096          // 16384: L2 fwd B-frags, K=128, scaled 2log2e
#define OFF_W2T 20480         // 16384: L2 bwd B-frags, K=128, scaled S1/S2=4
#define OFF_W1T 36864         // 2048 : L1 bwd B-frags, K=128 (cols>=8 zero)
#define WTOT    38912

__device__ __forceinline__ unsigned char to_fp8(float x) {
    return (unsigned char)(__builtin_amdgcn_cvt_pk_fp8_f32(x, x, 0, false) & 0xff);
}
__device__ __forceinline__ float fexp2(float x) {
#if __has_builtin(__builtin_amdgcn_exp2f)
    return __builtin_amdgcn_exp2f(x);
#else
    return exp2f(x);
#endif
}
__device__ __forceinline__ float frcp(float x) {
#if __has_builtin(__builtin_amdgcn_rcpf)
    return __builtin_amdgcn_rcpf(x);
#else
    return 1.0f / x;
#endif
}

// hardware transpose read: lane gathers 8 bytes at stride 16 from its own address
__device__ __forceinline__ i32x2 tr8(unsigned char* p) {
#if __has_builtin(__builtin_amdgcn_ds_read_tr8_b64)
    return __builtin_amdgcn_ds_read_tr8_b64((__attribute__((address_space(3))) i32x2*)p);
#else
    i32x2 d;
    asm volatile("ds_read_b64_tr_b8 %0, %1\n\ts_waitcnt lgkmcnt(0)"
                 : "=v"(d)
                 : "v"((unsigned)(unsigned long long)(__attribute__((address_space(3))) void*)p)
                 : "memory");
    __builtin_amdgcn_sched_barrier(0);
    return d;
#endif
}

// A-fragment for K=128: 4 transposed b64 reads, chunk c at +c*512 (32 cols * 16B)
__device__ __forceinline__ i32x8 read_a(unsigned char* abase) {
    i32x2 a0 = tr8(abase);
    i32x2 a1 = tr8(abase + 512);
    i32x2 a2 = tr8(abase + 1024);
    i32x2 a3 = tr8(abase + 1536);
    return (i32x8){a0[0], a0[1], a1[0], a1[1], a2[0], a2[1], a3[0], a3[1]};
}

// K=128 fp8 matmul-accumulate, unit block scales; fallback = 4 x K=32 (same byte map)
__device__ __forceinline__ f32x4 mm128(i32x8 a, i32x8 b, f32x4 c) {
#if __has_builtin(__builtin_amdgcn_mfma_scale_f32_16x16x128_f8f6f4)
    return __builtin_amdgcn_mfma_scale_f32_16x16x128_f8f6f4(a, b, c, 0, 0, 0, SCL1, 0, SCL1);
#else
    #pragma unroll
    for (int kt = 0; kt < 4; kt++) {
        long long aa = ((long long)(unsigned)a[2 * kt + 1] << 32) | (unsigned)a[2 * kt];
        long long bb = ((long long)(unsigned)b[2 * kt + 1] << 32) | (unsigned)b[2 * kt];
        c = __builtin_amdgcn_mfma_f32_16x16x32_fp8_fp8(aa, bb, c, 0, 0, 0);
    }
    return c;
#endif
}

// ---------------- prep: swizzle fp8 weight fragments into workspace ----------------
__global__ __launch_bounds__(256) void hnn_prep_kernel(
    const float* __restrict__ W1, const float* __restrict__ W2,
    unsigned char* __restrict__ ws)
{
    const int t = threadIdx.x, b = blockIdx.x;
    if (b == 0) {
        for (int i = t; i < 1024; i += 256) ((int*)(ws + OFF_W1B))[i] = 0;
        for (int i = t; i < 512;  i += 256) ((int*)(ws + OFF_W1T))[i] = 0;
        __syncthreads();
        for (int i = t; i < 1024; i += 256) {
            int row = i >> 7, col = i & 127;          // W1[row][col]: row = dim k, col = hidden j
            float w = W1[i];
            // fwd (K=32): pos = nt*512 + lane*8 + b ; only qd=0 (k<8) nonzero
            ws[OFF_W1B + (col >> 4) * 512 + (col & 15) * 8 + row] = to_fp8(w * TWO_LOG2E);
            // bwd (K=128): k-dim = col, n = row
            int c = col >> 5, h = c >> 1, s = (c & 1) * 8 + (col & 7);
            int qd = (col >> 3) & 3;
            ws[OFF_W1T + (h * 64 + qd * 16 + row) * 16 + s] = to_fp8(w);
        }
    } else {
        int idx = (b - 1) * 256 + t;                  // 0..16383
        int row = idx >> 7, col = idx & 127;          // W2[row][col]
        float w = W2[idx];
        {   // fwd: k-dim = row (h1 index), n = col (h2 index)
            int c = row >> 5, h = c >> 1, s = (c & 1) * 8 + (row & 7);
            int qd = (row >> 3) & 3;
            ws[OFF_W2B + (((col >> 4) * 2 + h) * 64 + qd * 16 + (col & 15)) * 16 + s] =
                to_fp8(w * TWO_LOG2E);
        }
        {   // bwd: k-dim = col, n = row ; fold S1/S2
            int c = col >> 5, h = c >> 1, s = (c & 1) * 8 + (col & 7);
            int qd = (col >> 3) & 3;
            ws[OFF_W2T + (((row >> 4) * 2 + h) * 64 + qd * 16 + (row & 15)) * 16 + s] =
                to_fp8(w * 4.0f);
        }
    }
}

// ---------------- main: fused leapfrog ----------------
__global__ __launch_bounds__(256) void hnn_leapfrog_kernel(
    const float* __restrict__ Z, const unsigned char* __restrict__ WS,
    const float* __restrict__ B1f, const float* __restrict__ B2f,
    const float* __restrict__ W3, float* __restrict__ OUT)
{
    __shared__ __align__(16) unsigned char sWT[WTOT];       // all weight fragments
    __shared__ __align__(16) unsigned char sACT[4 * 2048];  // per-wave column-major act tile
    __shared__ __align__(16) float sZ[512];

    const int t   = threadIdx.x;
    const int blk = blockIdx.x;

    for (int i = t; i < WTOT / 16; i += 256)
        __builtin_amdgcn_global_load_lds(
            (const __attribute__((address_space(1))) void*)(WS + i * 16),
            (__attribute__((address_space(3))) void*)(sWT + i * 16), 16, 0, 0);
    sZ[t]       = Z[blk * 512 + t];
    sZ[t + 256] = Z[blk * 512 + 256 + t];

    const int lane = t & 63;
    const int wv   = t >> 6;
    const int nn   = lane & 15;
    const int qd   = lane >> 4;

    float b1v[8], b2v[8], w3v[8];
    #pragma unroll
    for (int nt = 0; nt < 8; nt++) {
        b1v[nt] = B1f[nt * 16 + nn] * TWO_LOG2E;            // bias pre-scaled for exp2
        b2v[nt] = B2f[nt * 16 + nn] * TWO_LOG2E;
        w3v[nt] = W3[nt * 16 + nn] * (4.0f * S2);           // 64*W3 for d2 = 64*W3*(r-r^2)
    }
    __syncthreads();
    // no further block barriers: each wave works on private LDS slices

    unsigned char* act   = sACT + wv * 2048;
    float*         zrow  = sZ + wv * 128;                   // wave's 16 rows x 8 floats
    unsigned char* abase = act + qd * 128 + nn;             // tr8 read base
    unsigned char* awr   = act + nn * 16 + qd * 4;          // packed C-store base (+nt*256)

    #pragma unroll 1
    for (int ev = 0; ev < 4; ev++) {
        // ================= L1 forward: h1 = tanh(z @ W1 + b1) =================
        long long az = 0;
        if (qd == 0) {
            const f32x4* zr = (const f32x4*)(zrow + nn * 8);
            f32x4 z0 = zr[0], z1 = zr[1];
            int lo = __builtin_amdgcn_cvt_pk_fp8_f32(z0[0], z0[1], 0, false);
            lo     = __builtin_amdgcn_cvt_pk_fp8_f32(z0[2], z0[3], lo, true);
            int hi = __builtin_amdgcn_cvt_pk_fp8_f32(z1[0], z1[1], 0, false);
            hi     = __builtin_amdgcn_cvt_pk_fp8_f32(z1[2], z1[3], hi, true);
            az = ((long long)(unsigned)hi << 32) | (unsigned)lo;
        }
        float hc[8][4];                                     // h1 kept for backward factor
        #pragma unroll
        for (int nt = 0; nt < 8; nt++) {
            long long bf = *(const long long*)(sWT + OFF_W1B + nt * 512 + lane * 8);
            f32x4 c = {b1v[nt], b1v[nt], b1v[nt], b1v[nt]};
            c = __builtin_amdgcn_mfma_f32_16x16x32_fp8_fp8(az, bf, c, 0, 0, 0);
            #pragma unroll
            for (int r = 0; r < 4; r++) {
                float e  = fexp2(c[r]);                     // input already *2log2e
                float rr = frcp(e + 1.0f);
                hc[nt][r] = fmaf(-2.0f, rr, 1.0f);          // tanh
            }
            int v = __builtin_amdgcn_cvt_pk_fp8_f32(hc[nt][0], hc[nt][1], 0, false);
            v     = __builtin_amdgcn_cvt_pk_fp8_f32(hc[nt][2], hc[nt][3], v, true);
            *(int*)(awr + nt * 256) = v;                    // conflict-free b32 store
        }
        // ================= L2 forward: d2 = 16*W3*(1-tanh^2(h1@W2+b2)) =================
        i32x8 a8 = read_a(abase);
        #pragma unroll
        for (int nt = 0; nt < 8; nt++) {
            i32x4 bA = *(const i32x4*)(sWT + OFF_W2B + nt * 2048 + lane * 16);
            i32x4 bB = *(const i32x4*)(sWT + OFF_W2B + nt * 2048 + 1024 + lane * 16);
            i32x8 b8 = {bA[0], bA[1], bA[2], bA[3], bB[0], bB[1], bB[2], bB[3]};
            f32x4 c = {b2v[nt], b2v[nt], b2v[nt], b2v[nt]};
            c = mm128(a8, b8, c);
            float dd[4];
            #pragma unroll
            for (int r = 0; r < 4; r++) {
                float e  = fexp2(c[r]);
                float rr = frcp(e + 1.0f);
                dd[r] = w3v[nt] * fmaf(-rr, rr, rr);        // 64*W3*(r-r^2) = 16*W3*(1-t^2)
            }
            int v = __builtin_amdgcn_cvt_pk_fp8_f32(dd[0], dd[1], 0, false);
            v     = __builtin_amdgcn_cvt_pk_fp8_f32(dd[2], dd[3], v, true);
            *(int*)(awr + nt * 256) = v;                    // overwrite h1 (consumed)
        }
        // ================= L2 backward: d1 = (1-h1^2)*(d2 @ 4*W2^T) =================
        a8 = read_a(abase);
        #pragma unroll
        for (int nt = 0; nt < 8; nt++) {
            i32x4 bA = *(const i32x4*)(sWT + OFF_W2T + nt * 2048 + lane * 16);
            i32x4 bB = *(const i32x4*)(sWT + OFF_W2T + nt * 2048 + 1024 + lane * 16);
            i32x8 b8 = {bA[0], bA[1], bA[2], bA[3], bB[0], bB[1], bB[2], bB[3]};
            f32x4 c = {0.f, 0.f, 0.f, 0.f};
            c = mm128(a8, b8, c);
            float dd[4];
            #pragma unroll
            for (int r = 0; r < 4; r++) {
                float h = hc[nt][r];
                dd[r] = c[r] * fmaf(-h, h, 1.0f);           // carries S1=64 scale
            }
            int v = __builtin_amdgcn_cvt_pk_fp8_f32(dd[0], dd[1], 0, false);
            v     = __builtin_amdgcn_cvt_pk_fp8_f32(dd[2], dd[3], v, true);
            *(int*)(awr + nt * 256) = v;
        }
        // ================= L1 backward: g = d1 @ W1^T (cols 0..7 valid) =================
        a8 = read_a(abase);
        i32x4 bA = *(const i32x4*)(sWT + OFF_W1T + lane * 16);
        i32x4 bB = *(const i32x4*)(sWT + OFF_W1T + 1024 + lane * 16);
        i32x8 b8 = {bA[0], bA[1], bA[2], bA[3], bB[0], bB[1], bB[2], bB[3]};
        f32x4 g = {0.f, 0.f, 0.f, 0.f};
        g = mm128(a8, b8, g);
        // ================= symplectic update (C-layout: col nn, rows qd*4+r) =================
        const bool first = (ev & 1) == 0;
        if (nn < 4) {
            float* p = zrow + qd * 32 + nn + 4;             // dHdq -> p -= 0.5*DT*g
            #pragma unroll
            for (int r = 0; r < 4; r++) p[r * 8] -= (0.5f * DT / S1) * g[r];
        } else if (nn < 8 && first) {
            float* p = zrow + qd * 32 + (nn - 4);           // dHdp -> q += DT*g
            #pragma unroll
            for (int r = 0; r < 4; r++) p[r * 8] += (DT / S1) * g[r];
        }
    }

    // ---- write back (coalesced per wave) ----
    OUT[blk * 512 + wv * 128 + lane]      = zrow[lane];
    OUT[blk * 512 + wv * 128 + 64 + lane] = zrow[64 + lane];
}

extern "C" void kernel_launch(void* const* d_in, const int* in_sizes, int n_in,
                              void* d_out, int out_size, void* d_ws, size_t ws_size,
                              hipStream_t stream) {
    const float* Z  = (const float*)d_in[0];
    const float* W1 = (const float*)d_in[1];
    const float* B1 = (const float*)d_in[2];
    const float* W2 = (const float*)d_in[3];
    const float* B2 = (const float*)d_in[4];
    const float* W3 = (const float*)d_in[5];
    float* OUT = (float*)d_out;
    unsigned char* ws = (unsigned char*)d_ws;
    int blocks = in_sizes[0] / 512;   // 64 batch rows per block
    hipLaunchKernelGGL(hnn_prep_kernel, dim3(65), dim3(256), 0, stream, W1, W2, ws);
    hipLaunchKernelGGL(hnn_leapfrog_kernel, dim3(blocks), dim3(256), 0, stream,
                       Z, ws, B1, B2, W3, OUT);
}

// Round 2
// 240.159 us; speedup vs baseline: 1.6621x; 1.1020x over previous
//
#include <hip/hip_runtime.h>

// SymplecticLayer: 2 leapfrog steps; force = grad of tanh-MLP Hamiltonian (8->128->128->1).
// v3 changes vs v2:
//   - block 512 (8 waves): LDS 59392 B -> 2 blocks/CU -> 16 waves/CU (was 12)
//   - biases folded multiplicatively: e^(y+b) = exp2(c)*eb, r = rcp(fmaf(e, eb, 1));
//     all MFMA accumulators init from a shared zero vector (no per-tile bias movs)
//   - W3 folded into W2T at prep (W2T' = 256*w3*W2); d2-frag stores rr-rr^2 = sech^2/4
//     (same per-operand fp8 quantization count as before; removes 32 muls/eval + 8 VGPRs)
//   - i32x8 operands assembled with __builtin_shufflevector; LDS reads off hoisted bases
//     so all tile offsets become ds_read immediate offsets

typedef float f32x4 __attribute__((ext_vector_type(4)));
typedef int   i32x2 __attribute__((ext_vector_type(2)));
typedef int   i32x4 __attribute__((ext_vector_type(4)));
typedef int   i32x8 __attribute__((ext_vector_type(8)));

#define DT 0.01f
#define S1 64.0f              // d1 scale (fp8 dynamic-range placement)
#define TWO_LOG2E 2.8853900817779268f
#define SCL1 0x7F7F7F7F       // e8m0 1.0 in all four bytes

// workspace / LDS fragment layout (fp8 bytes). K=128 regions use the byte map:
//   register byte p (0..31) of quad qd  <->  k = 32*(p>>3) + 8*qd + (p&7)
// identical on A and B sides, so any internal HW k-permutation cancels.
#define OFF_W1B 0             // 4096 : L1 fwd B-frags, K=32 (k>=8 zero), scaled 2log2e
#define OFF_W2B 4096          // 16384: L2 fwd B-frags, K=128, scaled 2log2e
#define OFF_W2T 20480         // 16384: L2 bwd B-frags, K=128, scaled 256*w3
#define OFF_W1T 36864         // 2048 : L1 bwd B-frags, K=128 (cols>=8 zero)
#define WTOT    38912

__device__ __forceinline__ unsigned char to_fp8(float x) {
    return (unsigned char)(__builtin_amdgcn_cvt_pk_fp8_f32(x, x, 0, false) & 0xff);
}
__device__ __forceinline__ float fexp2(float x) {
#if __has_builtin(__builtin_amdgcn_exp2f)
    return __builtin_amdgcn_exp2f(x);
#else
    return exp2f(x);
#endif
}
__device__ __forceinline__ float frcp(float x) {
#if __has_builtin(__builtin_amdgcn_rcpf)
    return __builtin_amdgcn_rcpf(x);
#else
    return 1.0f / x;
#endif
}

// hardware transpose read: lane gathers 8 bytes at stride 16 from its own address
__device__ __forceinline__ i32x2 tr8(unsigned char* p) {
#if __has_builtin(__builtin_amdgcn_ds_read_tr8_b64)
    return __builtin_amdgcn_ds_read_tr8_b64((__attribute__((address_space(3))) i32x2*)p);
#else
    i32x2 d;
    asm volatile("ds_read_b64_tr_b8 %0, %1\n\ts_waitcnt lgkmcnt(0)"
                 : "=v"(d)
                 : "v"((unsigned)(unsigned long long)(__attribute__((address_space(3))) void*)p)
                 : "memory");
    __builtin_amdgcn_sched_barrier(0);
    return d;
#endif
}

__device__ __forceinline__ i32x8 cat44(i32x4 a, i32x4 b) {
    return __builtin_shufflevector(a, b, 0, 1, 2, 3, 4, 5, 6, 7);
}

// A-fragment for K=128: 4 transposed b64 reads, chunk c at +c*512 (32 cols * 16B)
__device__ __forceinline__ i32x8 read_a(unsigned char* abase) {
    i32x2 a0 = tr8(abase);
    i32x2 a1 = tr8(abase + 512);
    i32x2 a2 = tr8(abase + 1024);
    i32x2 a3 = tr8(abase + 1536);
    i32x4 lo = __builtin_shufflevector(a0, a1, 0, 1, 2, 3);
    i32x4 hi = __builtin_shufflevector(a2, a3, 0, 1, 2, 3);
    return cat44(lo, hi);
}

// K=128 fp8 matmul-accumulate, unit block scales; fallback = 4 x K=32 (same byte map)
__device__ __forceinline__ f32x4 mm128(i32x8 a, i32x8 b, f32x4 c) {
#if __has_builtin(__builtin_amdgcn_mfma_scale_f32_16x16x128_f8f6f4)
    return __builtin_amdgcn_mfma_scale_f32_16x16x128_f8f6f4(a, b, c, 0, 0, 0, SCL1, 0, SCL1);
#else
    #pragma unroll
    for (int kt = 0; kt < 4; kt++) {
        long long aa = ((long long)(unsigned)a[2 * kt + 1] << 32) | (unsigned)a[2 * kt];
        long long bb = ((long long)(unsigned)b[2 * kt + 1] << 32) | (unsigned)b[2 * kt];
        c = __builtin_amdgcn_mfma_f32_16x16x32_fp8_fp8(aa, bb, c, 0, 0, 0);
    }
    return c;
#endif
}

// ---------------- prep: swizzle fp8 weight fragments into workspace ----------------
__global__ __launch_bounds__(256) void hnn_prep_kernel(
    const float* __restrict__ W1, const float* __restrict__ W2,
    const float* __restrict__ W3, unsigned char* __restrict__ ws)
{
    const int t = threadIdx.x, b = blockIdx.x;
    if (b == 0) {
        for (int i = t; i < 1024; i += 256) ((int*)(ws + OFF_W1B))[i] = 0;
        for (int i = t; i < 512;  i += 256) ((int*)(ws + OFF_W1T))[i] = 0;
        __syncthreads();
        for (int i = t; i < 1024; i += 256) {
            int row = i >> 7, col = i & 127;          // W1[row][col]: row = dim k, col = hidden j
            float w = W1[i];
            // fwd (K=32): pos = nt*512 + lane*8 + b ; only qd=0 (k<8) nonzero
            ws[OFF_W1B + (col >> 4) * 512 + (col & 15) * 8 + row] = to_fp8(w * TWO_LOG2E);
            // bwd (K=128): k-dim = col, n = row
            int c = col >> 5, h = c >> 1, s = (c & 1) * 8 + (col & 7);
            int qd = (col >> 3) & 3;
            ws[OFF_W1T + (h * 64 + qd * 16 + row) * 16 + s] = to_fp8(w);
        }
    } else {
        int idx = (b - 1) * 256 + t;                  // 0..16383
        int row = idx >> 7, col = idx & 127;          // W2[row][col]
        float w = W2[idx];
        {   // fwd: k-dim = row (h1 index), n = col (h2 index)
            int c = row >> 5, h = c >> 1, s = (c & 1) * 8 + (row & 7);
            int qd = (row >> 3) & 3;
            ws[OFF_W2B + (((col >> 4) * 2 + h) * 64 + qd * 16 + (col & 15)) * 16 + s] =
                to_fp8(w * TWO_LOG2E);
        }
        {   // bwd: k-dim = col, n = row ; fold 256*w3[col] (A-frag carries sech^2/4)
            int c = col >> 5, h = c >> 1, s = (c & 1) * 8 + (col & 7);
            int qd = (col >> 3) & 3;
            ws[OFF_W2T + (((row >> 4) * 2 + h) * 64 + qd * 16 + (row & 15)) * 16 + s] =
                to_fp8(w * 256.0f * W3[col]);
        }
    }
}

// ---------------- main: fused leapfrog ----------------
__global__ __launch_bounds__(512) void hnn_leapfrog_kernel(
    const float* __restrict__ Z, const unsigned char* __restrict__ WS,
    const float* __restrict__ B1f, const float* __restrict__ B2f,
    float* __restrict__ OUT)
{
    __shared__ __align__(16) unsigned char sWT[WTOT];       // all weight fragments
    __shared__ __align__(16) unsigned char sACT[8 * 2048];  // per-wave column-major act tile
    __shared__ __align__(16) float sZ[1024];

    const int t   = threadIdx.x;
    const int blk = blockIdx.x;

    for (int i = t; i < WTOT / 16; i += 512)
        __builtin_amdgcn_global_load_lds(
            (const __attribute__((address_space(1))) void*)(WS + i * 16),
            (__attribute__((address_space(3))) void*)(sWT + i * 16), 16, 0, 0);
    sZ[t]       = Z[blk * 1024 + t];
    sZ[t + 512] = Z[blk * 1024 + 512 + t];

    const int lane = t & 63;
    const int wv   = t >> 6;
    const int nn   = lane & 15;
    const int qd   = lane >> 4;

    // multiplicative bias folds: e^(y+b) = exp2(c) * eb  (exact f32, no fp8 bias quant)
    float eb1v[8], eb2v[8];
    #pragma unroll
    for (int nt = 0; nt < 8; nt++) {
        eb1v[nt] = fexp2(B1f[nt * 16 + nn] * TWO_LOG2E);
        eb2v[nt] = fexp2(B2f[nt * 16 + nn] * TWO_LOG2E);
    }
    __syncthreads();
    // no further block barriers: each wave works on private LDS slices

    unsigned char* act   = sACT + wv * 2048;
    float*         zrow  = sZ + wv * 128;                   // wave's 16 rows x 8 floats
    unsigned char* abase = act + qd * 128 + nn;             // tr8 read base
    unsigned char* awr   = act + nn * 16 + qd * 4;          // packed C-store base (+nt*256)
    const unsigned char* w8  = sWT + lane * 8;              // K=32 B-frag base
    const unsigned char* w16 = sWT + lane * 16;             // K=128 B-frag base

    const f32x4 zc = {0.f, 0.f, 0.f, 0.f};

    #pragma unroll 1
    for (int ev = 0; ev < 4; ev++) {
        // ================= L1 forward: h1 = tanh(z @ W1 + b1) =================
        long long az = 0;
        if (qd == 0) {
            const f32x4* zr = (const f32x4*)(zrow + nn * 8);
            f32x4 z0 = zr[0], z1 = zr[1];
            int lo = __builtin_amdgcn_cvt_pk_fp8_f32(z0[0], z0[1], 0, false);
            lo     = __builtin_amdgcn_cvt_pk_fp8_f32(z0[2], z0[3], lo, true);
            int hi = __builtin_amdgcn_cvt_pk_fp8_f32(z1[0], z1[1], 0, false);
            hi     = __builtin_amdgcn_cvt_pk_fp8_f32(z1[2], z1[3], hi, true);
            az = ((long long)(unsigned)hi << 32) | (unsigned)lo;
        }
        float hc[8][4];                                     // h1 kept for backward factor
        #pragma unroll
        for (int nt = 0; nt < 8; nt++) {
            long long bf = *(const long long*)(w8 + OFF_W1B + nt * 512);
            f32x4 c = __builtin_amdgcn_mfma_f32_16x16x32_fp8_fp8(az, bf, zc, 0, 0, 0);
            #pragma unroll
            for (int r = 0; r < 4; r++) {
                float e  = fexp2(c[r]);                     // input already *2log2e
                float rr = frcp(fmaf(e, eb1v[nt], 1.0f));   // 1/(e*eb+1)
                hc[nt][r] = fmaf(-2.0f, rr, 1.0f);          // tanh
            }
            int v = __builtin_amdgcn_cvt_pk_fp8_f32(hc[nt][0], hc[nt][1], 0, false);
            v     = __builtin_amdgcn_cvt_pk_fp8_f32(hc[nt][2], hc[nt][3], v, true);
            *(int*)(awr + nt * 256) = v;                    // conflict-free b32 store
        }
        // ================= L2 forward: store sech^2/4 = rr - rr^2 =================
        i32x8 a8 = read_a(abase);
        #pragma unroll
        for (int nt = 0; nt < 8; nt++) {
            i32x4 bA = *(const i32x4*)(w16 + OFF_W2B + nt * 2048);
            i32x4 bB = *(const i32x4*)(w16 + OFF_W2B + nt * 2048 + 1024);
            f32x4 c = mm128(a8, cat44(bA, bB), zc);
            float dd[4];
            #pragma unroll
            for (int r = 0; r < 4; r++) {
                float e  = fexp2(c[r]);
                float rr = frcp(fmaf(e, eb2v[nt], 1.0f));
                dd[r] = fmaf(-rr, rr, rr);                  // rr - rr^2 (w3 folded in W2T)
            }
            int v = __builtin_amdgcn_cvt_pk_fp8_f32(dd[0], dd[1], 0, false);
            v     = __builtin_amdgcn_cvt_pk_fp8_f32(dd[2], dd[3], v, true);
            *(int*)(awr + nt * 256) = v;                    // overwrite h1 (consumed)
        }
        // ================= L2 backward: d1 = (1-h1^2)*(a @ 256*w3*W2^T) =================
        a8 = read_a(abase);
        #pragma unroll
        for (int nt = 0; nt < 8; nt++) {
            i32x4 bA = *(const i32x4*)(w16 + OFF_W2T + nt * 2048);
            i32x4 bB = *(const i32x4*)(w16 + OFF_W2T + nt * 2048 + 1024);
            f32x4 c = mm128(a8, cat44(bA, bB), zc);
            float dd[4];
            #pragma unroll
            for (int r = 0; r < 4; r++) {
                float h = hc[nt][r];
                dd[r] = c[r] * fmaf(-h, h, 1.0f);           // carries S1=64 scale
            }
            int v = __builtin_amdgcn_cvt_pk_fp8_f32(dd[0], dd[1], 0, false);
            v     = __builtin_amdgcn_cvt_pk_fp8_f32(dd[2], dd[3], v, true);
            *(int*)(awr + nt * 256) = v;
        }
        // ================= L1 backward: g = d1 @ W1^T (cols 0..7 valid) =================
        a8 = read_a(abase);
        i32x4 bA = *(const i32x4*)(w16 + OFF_W1T);
        i32x4 bB = *(const i32x4*)(w16 + OFF_W1T + 1024);
        f32x4 g = mm128(a8, cat44(bA, bB), zc);
        // ================= symplectic update (C-layout: col nn, rows qd*4+r) =================
        const bool first = (ev & 1) == 0;
        if (nn < 4) {
            float* p = zrow + qd * 32 + nn + 4;             // dHdq -> p -= 0.5*DT*g
            #pragma unroll
            for (int r = 0; r < 4; r++) p[r * 8] -= (0.5f * DT / S1) * g[r];
        } else if (nn < 8 && first) {
            float* p = zrow + qd * 32 + (nn - 4);           // dHdp -> q += DT*g
            #pragma unroll
            for (int r = 0; r < 4; r++) p[r * 8] += (DT / S1) * g[r];
        }
    }

    // ---- write back (coalesced per wave) ----
    OUT[blk * 1024 + wv * 128 + lane]      = zrow[lane];
    OUT[blk * 1024 + wv * 128 + 64 + lane] = zrow[64 + lane];
}

extern "C" void kernel_launch(void* const* d_in, const int* in_sizes, int n_in,
                              void* d_out, int out_size, void* d_ws, size_t ws_size,
                              hipStream_t stream) {
    const float* Z  = (const float*)d_in[0];
    const float* W1 = (const float*)d_in[1];
    const float* B1 = (const float*)d_in[2];
    const float* W2 = (const float*)d_in[3];
    const float* B2 = (const float*)d_in[4];
    const float* W3 = (const float*)d_in[5];
    float* OUT = (float*)d_out;
    unsigned char* ws = (unsigned char*)d_ws;
    int blocks = in_sizes[0] / 1024;   // 128 batch rows per block
    hipLaunchKernelGGL(hnn_prep_kernel, dim3(65), dim3(256), 0, stream, W1, W2, W3, ws);
    hipLaunchKernelGGL(hnn_leapfrog_kernel, dim3(blocks), dim3(512), 0, stream,
                       Z, ws, B1, B2, OUT);
}